// Round 11
// baseline (137.651 us; speedup 1.0000x reference)
//
#include <hip/hip_runtime.h>

#define S_LEN 2048
#define D_MODEL 512
#define NHEAD 8
#define BATCH 2

typedef __attribute__((ext_vector_type(8))) short bf16x8;
typedef __attribute__((ext_vector_type(4))) float f32x4;

__device__ __forceinline__ unsigned short f2bf(float f) {
    union { float f; unsigned u; } v; v.f = f;
    unsigned u = v.u + 0x7FFFu + ((v.u >> 16) & 1u);   // RNE
    return (unsigned short)(u >> 16);
}

// 2^x via v_exp_f32 (native). exp2(-inf)=0 in HW, which the masking relies on.
__device__ __forceinline__ float ex2(float x) {
    return __builtin_amdgcn_exp2f(x);
}

// pack two f32 -> two bf16 in one dword (RNE), 1 instr vs ~12 ALU ops
__device__ __forceinline__ unsigned cvtpk(float lo, float hi) {
    unsigned r;
    asm("v_cvt_pk_bf16_f32 %0, %1, %2" : "=v"(r) : "v"(lo), "v"(hi));
    return r;
}

// async global->LDS, 16B per lane, LDS dest = wave-uniform base + lane*16
__device__ __forceinline__ void gl_lds16(const unsigned short* g, unsigned short* l) {
    __builtin_amdgcn_global_load_lds(
        (const __attribute__((address_space(1))) void*)g,
        (__attribute__((address_space(3))) void*)l,
        16, 0, 0);
}

// --------------------------------------------- lens + W fp32->bf16 convert --
__global__ __launch_bounds__(256) void cvtlens_kernel(
    const float* __restrict__ WQ, const float* __restrict__ WK,
    const float* __restrict__ WV, const float* __restrict__ WO,
    const int* __restrict__ rpm, const int* __restrict__ cpm,
    unsigned short* __restrict__ Wbf, int* __restrict__ lens)
{
    const int t = threadIdx.x;
    if (blockIdx.x < 2) {
        __shared__ int red[256];
        const int b = blockIdx.x;
        int sr = 0, sc2 = 0;
        for (int i = t; i < S_LEN; i += 256) {
            sr  += rpm[b * S_LEN + i];
            sc2 += cpm[b * S_LEN + i];
        }
        red[t] = sr;
        __syncthreads();
        for (int off = 128; off > 0; off >>= 1) {
            if (t < off) red[t] += red[t + off];
            __syncthreads();
        }
        if (t == 0) lens[b * 2 + 0] = red[0];
        __syncthreads();
        red[t] = sc2;
        __syncthreads();
        for (int off = 128; off > 0; off >>= 1) {
            if (t < off) red[t] += red[t + off];
            __syncthreads();
        }
        if (t == 0) lens[b * 2 + 1] = red[0];
    }

    const int NW = 131072;           // 4*512*512/8 chunks
    const int stride = gridDim.x * 256;
    for (int c = blockIdx.x * 256 + t; c < NW; c += stride) {
        const int wflat = c << 3;
        const int wz = wflat >> 18;
        const int off = wflat & 262143;
        const float* src = ((wz == 0) ? WQ : (wz == 1) ? WK : (wz == 2) ? WV : WO) + off;
        float4 a = *(const float4*)src;
        float4 d = *(const float4*)(src + 4);
        unsigned short* w = Wbf + wflat;
        w[0] = f2bf(a.x); w[1] = f2bf(a.y); w[2] = f2bf(a.z); w[3] = f2bf(a.w);
        w[4] = f2bf(d.x); w[5] = f2bf(d.y); w[6] = f2bf(d.z); w[7] = f2bf(d.w);
    }
}

// --------------------------------------------------------- projection GEMM --
// BM=64 x BN=128 tiles, BK=64, double-buffered, 768 blocks = 3/CU (48 KB).
// 1D grid with XCD-locality decode: all 12 blocks (4 tileF x 3 z) sharing
// one 64-row X panel get the same id%8 -> same XCD under round-robin
// dispatch -> X panel is an L2 hit after first touch (panels/XCD ~1 MB).
__global__ __launch_bounds__(256) void proj_gemm(
    const float* __restrict__ inQ, const float* __restrict__ inK,
    const float* __restrict__ inV, const unsigned short* __restrict__ Wbf,
    const float* __restrict__ bQ, const float* __restrict__ bK, const float* __restrict__ bV,
    const int* __restrict__ lens,
    unsigned short* __restrict__ Qg, unsigned short* __restrict__ Kg,
    unsigned short* __restrict__ VTg)
{
    __shared__ __align__(16) unsigned short Xld[2][4096];
    __shared__ __align__(16) unsigned short Wld[2][8192];

    // id = (x%8) + 8*((y*3+z) + 12*(x/8)); bijective over 768
    const int id = blockIdx.x;
    const int xcd = id & 7;
    const int rest = id >> 3;
    const int yz = rest % 12;
    const int x_hi = rest / 12;
    const int bx = x_hi * 8 + xcd;
    const int by = yz / 3;
    const int z  = yz % 3;

    const int tileS = bx * 64;
    const int tileF = by * 128;
    const int bb0 = tileS >> 11;
    const int rl = lens[bb0 * 2], cl = lens[bb0 * 2 + 1];
    const int limit = (z == 0) ? rl : cl;
    if ((tileS & 2047) >= limit) return;       // fully padded tile: outputs unused

    const float* Xs = (z == 0) ? inQ : (z == 1) ? inK : inV;   // [4096][512] f32
    const unsigned short* W = Wbf + (size_t)z * (512 * 512);
    const float* bias = (z == 0) ? bQ : (z == 1) ? bK : bV;

    const int t = threadIdx.x;
    const int wv = t >> 6, lane = t & 63, l15 = lane & 15, quad = lane >> 4;
    const int ro = lane >> 3;                 // row within 8-row staging group
    const int lc8 = ((lane & 7) ^ ro) * 8;    // swizzled source chunk (elements)

    const float* gXf = Xs + (size_t)(tileS + wv * 16 + ro) * 512 + lc8;
    const unsigned short* gW = W + (size_t)(tileF + wv * 32 + ro) * 512 + lc8;
    const int wvo = wv * 2048;                 // W: 32 rows/wave
    const int xdst = wv * 1024 + lane * 8;     // X: 16 rows/wave, lane*16B dest

    const int f_off = (wv & 1) * 64, s_off = (wv >> 1) * 32;
    const int swk = l15 & 7;

    f32x4 acc[4][2] = {};

    // prologue: stage chunk 0 into buffer 0
    #pragma unroll
    for (int j = 0; j < 2; ++j) {
        const float* s = gXf + j * 4096;      // j*8 rows
        float4 a = *(const float4*)s;
        float4 d = *(const float4*)(s + 4);
        uint4 u;
        u.x = cvtpk(a.x, a.y); u.y = cvtpk(a.z, a.w);
        u.z = cvtpk(d.x, d.y); u.w = cvtpk(d.z, d.w);
        *(uint4*)&Xld[0][xdst + j * 512] = u;
    }
    #pragma unroll
    for (int j = 0; j < 4; ++j)
        gl_lds16(gW + j * 4096, &Wld[0][wvo + j * 512]);

    for (int kk = 0; kk < 8; ++kk) {
        __syncthreads();                       // drains W gl_lds + X ds_writes
        float4 xa[2], xd[2];
        if (kk < 7) {                          // issue prefetch for chunk kk+1
            const int k0 = (kk + 1) * 64;
            #pragma unroll
            for (int j = 0; j < 2; ++j) {
                const float* s = gXf + k0 + j * 4096;
                xa[j] = *(const float4*)s;
                xd[j] = *(const float4*)(s + 4);
            }
            #pragma unroll
            for (int j = 0; j < 4; ++j)
                gl_lds16(gW + k0 + j * 4096, &Wld[(kk + 1) & 1][wvo + j * 512]);
        }
        const unsigned short* Xb = Xld[kk & 1];
        const unsigned short* Wb = Wld[kk & 1];
        #pragma unroll
        for (int kk2 = 0; kk2 < 2; ++kk2) {
            bf16x8 wf[4], xf[2];
            #pragma unroll
            for (int i = 0; i < 4; ++i) {
                const int rw = f_off + i * 16 + l15;
                wf[i] = *(const bf16x8*)(Wb + rw * 64 + ((kk2 * 4 + quad) ^ swk) * 8);
            }
            #pragma unroll
            for (int i = 0; i < 2; ++i) {
                const int rx = s_off + i * 16 + l15;
                xf[i] = *(const bf16x8*)(Xb + rx * 64 + ((kk2 * 4 + quad) ^ swk) * 8);
            }
            #pragma unroll
            for (int ft = 0; ft < 4; ++ft)
                #pragma unroll
                for (int st = 0; st < 2; ++st)
                    acc[ft][st] = __builtin_amdgcn_mfma_f32_16x16x32_bf16(
                        wf[ft], xf[st], acc[ft][st], 0, 0, 0);
        }
        if (kk < 7) {                          // convert + write AFTER compute
            const int nb = (kk + 1) & 1;
            #pragma unroll
            for (int j = 0; j < 2; ++j) {
                uint4 u;
                u.x = cvtpk(xa[j].x, xa[j].y); u.y = cvtpk(xa[j].z, xa[j].w);
                u.z = cvtpk(xd[j].x, xd[j].y); u.w = cvtpk(xd[j].z, xd[j].w);
                *(uint4*)&Xld[nb][xdst + j * 512] = u;
            }
        }
    }

    // fold 1/sqrt(dk) AND log2(e) into Q so attention can use exp2 directly
    const float oscale = (z == 0) ? 0.18033688011112042f : 1.0f;
    #pragma unroll
    for (int ft = 0; ft < 4; ++ft) {
        const int f = tileF + f_off + ft * 16 + quad * 4;
        const int h = f >> 6, dk = f & 63;
        const float b0 = bias[f], b1 = bias[f + 1], b2 = bias[f + 2], b3 = bias[f + 3];
        #pragma unroll
        for (int st = 0; st < 2; ++st) {
            const int s = tileS + s_off + st * 16 + l15;
            const int bb = s >> 11, seq = s & 2047;
            const f32x4 a = acc[ft][st];
            if (z <= 1) {
                unsigned short* dst = ((z == 0) ? Qg : Kg)
                    + ((size_t)((bb * 8 + h) * 2048 + seq)) * 64 + dk;
                ushort4 u;
                u.x = f2bf((a[0] + b0) * oscale); u.y = f2bf((a[1] + b1) * oscale);
                u.z = f2bf((a[2] + b2) * oscale); u.w = f2bf((a[3] + b3) * oscale);
                *(ushort4*)dst = u;
            } else {
                unsigned short* dst = VTg
                    + ((size_t)((bb * 8 + h) * 64 + dk)) * 2048 + seq;
                dst[0]    = f2bf(a[0] + b0);
                dst[2048] = f2bf(a[1] + b1);
                dst[4096] = f2bf(a[2] + b2);
                dst[6144] = f2bf(a[3] + b3);
            }
        }
    }
}

// ----------------------------------------------------------- attention ------
// Flash-decoding, 4 waves split the kv loop; QBLK=32 with swapped QK^T +
// permuted K-rows (identity PV A-fragments, in-lane softmax). 1D grid with
// XCD-locality decode: all 64 q0-blocks of one head share id%8 -> same XCD
// -> that head's K/V (512 KB) stays L2-resident instead of being refetched
// by 8 XCDs.
__global__ __launch_bounds__(256) void attn_kernel(
    const unsigned short* __restrict__ Qg, const unsigned short* __restrict__ Kg,
    const unsigned short* __restrict__ VTg, const int* __restrict__ lens,
    unsigned short* __restrict__ AO)
{
    __shared__ __align__(16) char smem[35840];
    unsigned short* stage = (unsigned short*)smem;              // 4 x 4096 shorts
    float* Ml = (float*)(smem + 34816);                         // 128
    float* Ll = Ml + 128;                                       // 128

    const int t = threadIdx.x;
    const int wv = t >> 6, lane = t & 63, l15 = lane & 15, quad = lane >> 4;

    // id = (bh%8) + 8*(q0i + 64*(bh/8)); bijective over 1024
    const int id = blockIdx.x;
    const int xcd = id & 7;
    const int rest = id >> 3;
    const int q0i = rest % 64;
    const int bh = (rest / 64) * 8 + xcd;

    const int b = bh >> 3, h = bh & 7;
    const int q0 = q0i * 32;
    const int rl = lens[b * 2], cl = lens[b * 2 + 1];

    if (q0 >= rl) {                            // fully masked rows -> zeros
        const int row = t >> 4, cg = t & 15;
        ushort4 zz = {0, 0, 0, 0};
        #pragma unroll
        for (int rr = 0; rr < 2; ++rr)
            *(ushort4*)(AO + ((size_t)(b * 2048 + q0 + rr * 16 + row)) * 512
                        + h * 64 + cg * 4) = zz;
        return;
    }

    bf16x8 aq[2][2];
    #pragma unroll
    for (int qs = 0; qs < 2; ++qs) {
        const unsigned short* Qrow = Qg + ((size_t)(bh * 2048 + q0 + qs * 16 + l15)) * 64;
        aq[qs][0] = *(const bf16x8*)(Qrow + quad * 8);
        aq[qs][1] = *(const bf16x8*)(Qrow + 32 + quad * 8);
    }

    unsigned short* stw = stage + wv * 4096;   // this wave's 8 KB tile buffer

    const int sro = lane >> 3;                              // staging row-in-group
    const int c0 = (((lane & 7) ^ (sro & 3)) << 3);         // staging col chunk base
    const int sk = l15 & 7;                                 // = s(g(ct,l15)), all ct
    const int sv = (l15 & 3) | ((l15 & 8) >> 1);            // = s(ct*16+l15), all ct
    const int skq0 = ((quad ^ sk) << 3), skq1 = (((quad + 4) ^ sk) << 3);
    const int svq0 = ((quad ^ sv) << 3), svq1 = (((quad + 4) ^ sv) << 3);

    f32x4 oacc[2][4] = {};
    float m_[2], l_[2];
    #pragma unroll
    for (int qs = 0; qs < 2; ++qs) { m_[qs] = -__builtin_inff(); l_[qs] = 0.f; }

    const int q_end = q0 + 32;
    const int kv_max = (cl < q_end) ? cl : q_end;
    const int ntiles = (kv_max + 63) >> 6;

    for (int kt = wv; kt < ntiles; kt += 4) {
        const int kv0 = kt * 64;

        {   // stage K tile (64 kv x 64 dk), swizzled source -> linear LDS
            const unsigned short* kgb = Kg + ((size_t)(bh * 2048 + kv0 + sro)) * 64;
            #pragma unroll
            for (int j = 0; j < 8; ++j)
                gl_lds16(kgb + j * 512 + (c0 ^ ((j & 1) << 5)), stw + j * 512);
        }
        __builtin_amdgcn_s_waitcnt(0x0070);    // vmcnt(0)+lgkmcnt(0): K staged

        f32x4 sc[2][4];
        __builtin_amdgcn_s_setprio(1);
        #pragma unroll
        for (int ct = 0; ct < 4; ++ct) {
            // permuted K-row assignment (see header comment)
            const int grow = ((l15 >> 2) << 3) + ((ct & 1) << 2) + (l15 & 3)
                           + ((ct >> 1) << 5);
            const unsigned short* krow = stw + grow * 64;
            const bf16x8 kf0 = *(const bf16x8*)(krow + skq0);
            const bf16x8 kf1 = *(const bf16x8*)(krow + skq1);
            #pragma unroll
            for (int qs = 0; qs < 2; ++qs) {
                f32x4 zz = {};
                zz = __builtin_amdgcn_mfma_f32_16x16x32_bf16(kf0, aq[qs][0], zz, 0, 0, 0);
                sc[qs][ct] = __builtin_amdgcn_mfma_f32_16x16x32_bf16(kf1, aq[qs][1], zz, 0, 0, 0);
            }
        }
        __builtin_amdgcn_s_setprio(0);
        __builtin_amdgcn_s_waitcnt(0x0070);    // K frag ds_reads done -> region free

        {   // stage V^T tile (64 dk x 64 kv); latency hides under softmax
            const unsigned short* vgb = VTg + ((size_t)(bh * 64 + sro)) * 2048 + kv0;
            #pragma unroll
            for (int j = 0; j < 8; ++j)
                gl_lds16(vgb + j * 16384 + (c0 ^ ((j & 1) << 5)), stw + j * 512);
        }

        const bool full = (kv0 + 64 <= q0) && (kv0 + 64 <= cl) && (q_end <= rl);

        union { bf16x8 v; unsigned u[4]; } P0[2], P1[2];
        #pragma unroll
        for (int qs = 0; qs < 2; ++qs) {
            const int qme = q0 + qs * 16 + l15;    // this lane's q row
            if (!full) {
                #pragma unroll
                for (int ct = 0; ct < 4; ++ct) {
                    const int kvb = kv0 + quad * 8 + ((ct & 1) << 2) + ((ct >> 1) << 5);
                    #pragma unroll
                    for (int r = 0; r < 4; ++r) {
                        const int kv = kvb + r;
                        const bool valid = (qme < rl) && (kv < cl) && (kv <= qme);
                        sc[qs][ct][r] = valid ? sc[qs][ct][r] : -__builtin_inff();
                    }
                }
            }

            // row max: in-lane tree over 16, then butterfly across the 4 quads
            float mx = -__builtin_inff();
            #pragma unroll
            for (int ct = 0; ct < 4; ++ct)
                mx = fmaxf(mx, fmaxf(fmaxf(sc[qs][ct][0], sc[qs][ct][1]),
                                     fmaxf(sc[qs][ct][2], sc[qs][ct][3])));
            mx = fmaxf(mx, __shfl_xor(mx, 16));
            mx = fmaxf(mx, __shfl_xor(mx, 32));

            const float mnew = fmaxf(m_[qs], mx);
            const float alpha = (m_[qs] == -__builtin_inff()) ? 0.f : ex2(m_[qs] - mnew);
            const float mden = (mnew == -__builtin_inff()) ? 0.f : mnew;

            float psum = 0.f;
            #pragma unroll
            for (int ct = 0; ct < 4; ++ct) {
                #pragma unroll
                for (int r = 0; r < 4; ++r)
                    sc[qs][ct][r] = ex2(sc[qs][ct][r] - mden);
                psum += (sc[qs][ct][0] + sc[qs][ct][1]) + (sc[qs][ct][2] + sc[qs][ct][3]);
            }
            psum += __shfl_xor(psum, 16);
            psum += __shfl_xor(psum, 32);
            l_[qs] = alpha * l_[qs] + psum;
            m_[qs] = mnew;

            // redistribute alpha from q=l15 layout to oacc's q=quad*4+r rows
            const float ar0 = __shfl(alpha, quad * 4 + 0);
            const float ar1 = __shfl(alpha, quad * 4 + 1);
            const float ar2 = __shfl(alpha, quad * 4 + 2);
            const float ar3 = __shfl(alpha, quad * 4 + 3);
            #pragma unroll
            for (int ct = 0; ct < 4; ++ct) {
                oacc[qs][ct][0] *= ar0; oacc[qs][ct][1] *= ar1;
                oacc[qs][ct][2] *= ar2; oacc[qs][ct][3] *= ar3;
            }

            // pack P in-register: identity PV A-fragments, zero shuffles/LDS
            P0[qs].u[0] = cvtpk(sc[qs][0][0], sc[qs][0][1]);
            P0[qs].u[1] = cvtpk(sc[qs][0][2], sc[qs][0][3]);
            P0[qs].u[2] = cvtpk(sc[qs][1][0], sc[qs][1][1]);
            P0[qs].u[3] = cvtpk(sc[qs][1][2], sc[qs][1][3]);
            P1[qs].u[0] = cvtpk(sc[qs][2][0], sc[qs][2][1]);
            P1[qs].u[1] = cvtpk(sc[qs][2][2], sc[qs][2][3]);
            P1[qs].u[2] = cvtpk(sc[qs][3][0], sc[qs][3][1]);
            P1[qs].u[3] = cvtpk(sc[qs][3][2], sc[qs][3][3]);
        }

        __builtin_amdgcn_s_waitcnt(0x0070);    // V^T staged
        __builtin_amdgcn_s_setprio(1);
        #pragma unroll
        for (int ct = 0; ct < 4; ++ct) {
            const unsigned short* vrow = stw + (ct * 16 + l15) * 64;
            const bf16x8 vf0 = *(const bf16x8*)(vrow + svq0);
            const bf16x8 vf1 = *(const bf16x8*)(vrow + svq1);
            #pragma unroll
            for (int qs = 0; qs < 2; ++qs) {
                oacc[qs][ct] = __builtin_amdgcn_mfma_f32_16x16x32_bf16(P0[qs].v, vf0, oacc[qs][ct], 0, 0, 0);
                oacc[qs][ct] = __builtin_amdgcn_mfma_f32_16x16x32_bf16(P1[qs].v, vf1, oacc[qs][ct], 0, 0, 0);
            }
        }
        __builtin_amdgcn_s_setprio(0);
    }

    // publish m,l partials (separate region, safe before barrier)
    if (lane < 16) {
        #pragma unroll
        for (int qs = 0; qs < 2; ++qs) {
            Ml[wv * 32 + qs * 16 + l15] = m_[qs];
            Ll[wv * 32 + qs * 16 + l15] = l_[qs];
        }
    }
    __syncthreads();                           // all waves done with staging

    // O partials alias the staging region (stride 68 floats: 2-way only)
    float* Po = (float*)smem;
    #pragma unroll
    for (int qs = 0; qs < 2; ++qs)
        #pragma unroll
        for (int ct = 0; ct < 4; ++ct)
            #pragma unroll
            for (int r = 0; r < 4; ++r)
                Po[wv * 2176 + (qs * 16 + quad * 4 + r) * 68 + ct * 16 + l15] = oacc[qs][ct][r];
    __syncthreads();

    // merge 4 partials; each thread handles 2 of the 32 rows
    const int row = t >> 4, cg = t & 15;
    #pragma unroll
    for (int rr = 0; rr < 2; ++rr) {
        const int orow = rr * 16 + row;
        float mw[4];
        float mstar = -__builtin_inff();
        #pragma unroll
        for (int w = 0; w < 4; ++w) {
            mw[w] = Ml[w * 32 + orow];
            mstar = fmaxf(mstar, mw[w]);
        }
        f32x4 o = {};
        if (mstar != -__builtin_inff()) {
            float lst = 0.f;
            #pragma unroll
            for (int w = 0; w < 4; ++w) {
                const float sw = (mw[w] == -__builtin_inff()) ? 0.f : ex2(mw[w] - mstar);
                lst += sw * Ll[w * 32 + orow];
                const f32x4 pv = *(const f32x4*)&Po[w * 2176 + orow * 68 + cg * 4];
                o[0] += sw * pv[0]; o[1] += sw * pv[1];
                o[2] += sw * pv[2]; o[3] += sw * pv[3];
            }
            const float inv = (lst > 0.f) ? 1.f / lst : 0.f;
            o[0] *= inv; o[1] *= inv; o[2] *= inv; o[3] *= inv;
        }
        ushort4 u;
        u.x = f2bf(o[0]); u.y = f2bf(o[1]); u.z = f2bf(o[2]); u.w = f2bf(o[3]);
        *(ushort4*)(AO + ((size_t)(b * 2048 + q0 + orow)) * 512 + h * 64 + cg * 4) = u;
    }
}

// ------------------------------------------------------------- output GEMM --
// BM=64 x BN=128 tiles, 256 blocks = 1/CU. 1D grid with XCD-locality
// decode: the 4 tileF blocks sharing one AO panel get the same id%8.
__global__ __launch_bounds__(256) void out_gemm(
    const unsigned short* __restrict__ AO, const unsigned short* __restrict__ Wbf,
    const float* __restrict__ bO, const int* __restrict__ lens, float* __restrict__ out)
{
    __shared__ __align__(16) unsigned short Xld[2][4096];
    __shared__ __align__(16) unsigned short Wld[2][8192];

    // id = (x%8) + 8*(y + 4*(x/8)); bijective over 256
    const int id = blockIdx.x;
    const int xcd = id & 7;
    const int rest = id >> 3;
    const int by = rest % 4;
    const int bx = (rest / 4) * 8 + xcd;

    const int tileS = bx * 64;
    const int tileF = by * 128;
    const int bb0 = tileS >> 11;
    const int rl = lens[bb0 * 2];
    const int t = threadIdx.x;

    if ((tileS & 2047) >= rl) {                // padded rows: out = bias
        const int r0 = t >> 2;
        const int cg = (t & 3) * 32;
        float4 bv[8];
        #pragma unroll
        for (int j = 0; j < 8; ++j) bv[j] = *(const float4*)(bO + tileF + cg + j * 4);
        float* orow = out + (size_t)(tileS + r0) * 512 + tileF + cg;
        #pragma unroll
        for (int j = 0; j < 8; ++j) *(float4*)(orow + j * 4) = bv[j];
        return;
    }

    const unsigned short* W = Wbf + (size_t)3 * (512 * 512);
    const int wv = t >> 6, lane = t & 63, l15 = lane & 15, quad = lane >> 4;
    const int ro = lane >> 3;
    const int lc8 = ((lane & 7) ^ ro) * 8;

    const unsigned short* gX = AO + (size_t)(tileS + wv * 16 + ro) * 512 + lc8;
    const unsigned short* gW = W + (size_t)(tileF + wv * 32 + ro) * 512 + lc8;
    const int xvo = wv * 1024;                 // X: 16 rows/wave
    const int wvo = wv * 2048;                 // W: 32 rows/wave

    const int f_off = (wv & 1) * 64, s_off = (wv >> 1) * 32;
    const int swk = l15 & 7;

    f32x4 acc[4][2] = {};

    #pragma unroll
    for (int j = 0; j < 2; ++j)
        gl_lds16(gX + j * 4096, &Xld[0][xvo + j * 512]);
    #pragma unroll
    for (int j = 0; j < 4; ++j)
        gl_lds16(gW + j * 4096, &Wld[0][wvo + j * 512]);

    for (int kk = 0; kk < 8; ++kk) {
        __syncthreads();
        if (kk < 7) {
            const int k0 = (kk + 1) * 64;
            const int nb = (kk + 1) & 1;
            #pragma unroll
            for (int j = 0; j < 2; ++j)
                gl_lds16(gX + k0 + j * 4096, &Xld[nb][xvo + j * 512]);
            #pragma unroll
            for (int j = 0; j < 4; ++j)
                gl_lds16(gW + k0 + j * 4096, &Wld[nb][wvo + j * 512]);
        }
        const unsigned short* Xb = Xld[kk & 1];
        const unsigned short* Wb = Wld[kk & 1];
        #pragma unroll
        for (int kk2 = 0; kk2 < 2; ++kk2) {
            bf16x8 wf[4], xf[2];
            #pragma unroll
            for (int i = 0; i < 4; ++i) {
                const int rw = f_off + i * 16 + l15;
                wf[i] = *(const bf16x8*)(Wb + rw * 64 + ((kk2 * 4 + quad) ^ swk) * 8);
            }
            #pragma unroll
            for (int i = 0; i < 2; ++i) {
                const int rx = s_off + i * 16 + l15;
                xf[i] = *(const bf16x8*)(Xb + rx * 64 + ((kk2 * 4 + quad) ^ swk) * 8);
            }
            #pragma unroll
            for (int ft = 0; ft < 4; ++ft)
                #pragma unroll
                for (int st = 0; st < 2; ++st)
                    acc[ft][st] = __builtin_amdgcn_mfma_f32_16x16x32_bf16(
                        wf[ft], xf[st], acc[ft][st], 0, 0, 0);
        }
    }

    #pragma unroll
    for (int ft = 0; ft < 4; ++ft) {
        const int f = tileF + f_off + ft * 16 + quad * 4;
        const float4 bv = *(const float4*)(bO + f);
        #pragma unroll
        for (int st = 0; st < 2; ++st) {
            const int s = tileS + s_off + st * 16 + l15;
            float4 o;
            o.x = acc[ft][st][0] + bv.x;
            o.y = acc[ft][st][1] + bv.y;
            o.z = acc[ft][st][2] + bv.z;
            o.w = acc[ft][st][3] + bv.w;
            *(float4*)(out + (size_t)s * 512 + f) = o;
        }
    }
}

// -------------------------------------------------------------- launch ------
extern "C" void kernel_launch(void* const* d_in, const int* in_sizes, int n_in,
                              void* d_out, int out_size, void* d_ws, size_t ws_size,
                              hipStream_t stream)
{
    const float* inQ = (const float*)d_in[0];
    const float* inK = (const float*)d_in[1];
    const float* inV = (const float*)d_in[2];
    const int*   rpm = (const int*)d_in[3];
    const int*   cpm = (const int*)d_in[4];
    const float* WQ  = (const float*)d_in[5];
    const float* bQ  = (const float*)d_in[6];
    const float* WK  = (const float*)d_in[7];
    const float* bK  = (const float*)d_in[8];
    const float* WV  = (const float*)d_in[9];
    const float* bV  = (const float*)d_in[10];
    const float* WO  = (const float*)d_in[11];
    const float* bO  = (const float*)d_in[12];
    float* out = (float*)d_out;

    char* ws = (char*)d_ws;
    unsigned short* Wbf = (unsigned short*)(ws + 12582912);      //  2 MB
    unsigned short* Qg  = (unsigned short*)(ws + 14680064);      //  4 MB
    unsigned short* Kg  = (unsigned short*)(ws + 18874368);      //  4 MB
    unsigned short* VTg = (unsigned short*)(ws + 23068672);      //  4 MB
    unsigned short* AO  = (unsigned short*)(ws + 27262976);      //  4 MB
    int* lens           = (int*)(ws + 31457280);

    cvtlens_kernel<<<dim3(512), dim3(256), 0, stream>>>(
        WQ, WK, WV, WO, rpm, cpm, Wbf, lens);
    proj_gemm<<<dim3(768), dim3(256), 0, stream>>>(
        inQ, inK, inV, Wbf, bQ, bK, bV, lens, Qg, Kg, VTg);
    attn_kernel<<<dim3(1024), dim3(256), 0, stream>>>(Qg, Kg, VTg, lens, AO);
    out_gemm<<<dim3(256), dim3(256), 0, stream>>>(AO, Wbf, bO, lens, out);
}

// Round 12
// 135.196 us; speedup vs baseline: 1.0182x; 1.0182x over previous
//
#include <hip/hip_runtime.h>

#define S_LEN 2048
#define D_MODEL 512
#define NHEAD 8
#define BATCH 2

typedef __attribute__((ext_vector_type(8))) short bf16x8;
typedef __attribute__((ext_vector_type(4))) float f32x4;

__device__ __forceinline__ unsigned short f2bf(float f) {
    union { float f; unsigned u; } v; v.f = f;
    unsigned u = v.u + 0x7FFFu + ((v.u >> 16) & 1u);   // RNE
    return (unsigned short)(u >> 16);
}

// 2^x via v_exp_f32 (native). exp2(-inf)=0 in HW, which the masking relies on.
__device__ __forceinline__ float ex2(float x) {
    return __builtin_amdgcn_exp2f(x);
}

// pack two f32 -> two bf16 in one dword (RNE), 1 instr vs ~12 ALU ops
__device__ __forceinline__ unsigned cvtpk(float lo, float hi) {
    unsigned r;
    asm("v_cvt_pk_bf16_f32 %0, %1, %2" : "=v"(r) : "v"(lo), "v"(hi));
    return r;
}

// async global->LDS, 16B per lane, LDS dest = wave-uniform base + lane*16
__device__ __forceinline__ void gl_lds16(const unsigned short* g, unsigned short* l) {
    __builtin_amdgcn_global_load_lds(
        (const __attribute__((address_space(1))) void*)g,
        (__attribute__((address_space(3))) void*)l,
        16, 0, 0);
}

// --------------------------------------------- lens + W fp32->bf16 convert --
__global__ __launch_bounds__(256) void cvtlens_kernel(
    const float* __restrict__ WQ, const float* __restrict__ WK,
    const float* __restrict__ WV, const float* __restrict__ WO,
    const int* __restrict__ rpm, const int* __restrict__ cpm,
    unsigned short* __restrict__ Wbf, int* __restrict__ lens)
{
    const int t = threadIdx.x;
    if (blockIdx.x < 2) {
        __shared__ int red[256];
        const int b = blockIdx.x;
        int sr = 0, sc2 = 0;
        for (int i = t; i < S_LEN; i += 256) {
            sr  += rpm[b * S_LEN + i];
            sc2 += cpm[b * S_LEN + i];
        }
        red[t] = sr;
        __syncthreads();
        for (int off = 128; off > 0; off >>= 1) {
            if (t < off) red[t] += red[t + off];
            __syncthreads();
        }
        if (t == 0) lens[b * 2 + 0] = red[0];
        __syncthreads();
        red[t] = sc2;
        __syncthreads();
        for (int off = 128; off > 0; off >>= 1) {
            if (t < off) red[t] += red[t + off];
            __syncthreads();
        }
        if (t == 0) lens[b * 2 + 1] = red[0];
    }

    const int NW = 131072;           // 4*512*512/8 chunks
    const int stride = gridDim.x * 256;
    for (int c = blockIdx.x * 256 + t; c < NW; c += stride) {
        const int wflat = c << 3;
        const int wz = wflat >> 18;
        const int off = wflat & 262143;
        const float* src = ((wz == 0) ? WQ : (wz == 1) ? WK : (wz == 2) ? WV : WO) + off;
        float4 a = *(const float4*)src;
        float4 d = *(const float4*)(src + 4);
        unsigned short* w = Wbf + wflat;
        w[0] = f2bf(a.x); w[1] = f2bf(a.y); w[2] = f2bf(a.z); w[3] = f2bf(a.w);
        w[4] = f2bf(d.x); w[5] = f2bf(d.y); w[6] = f2bf(d.z); w[7] = f2bf(d.w);
    }
}

// --------------------------------------------------------- projection GEMM --
// BM=64 x BN=128 tiles, BK=64, double-buffered, 768 blocks = 3/CU (48 KB).
// 1D grid with XCD-locality decode.
__global__ __launch_bounds__(256) void proj_gemm(
    const float* __restrict__ inQ, const float* __restrict__ inK,
    const float* __restrict__ inV, const unsigned short* __restrict__ Wbf,
    const float* __restrict__ bQ, const float* __restrict__ bK, const float* __restrict__ bV,
    const int* __restrict__ lens,
    unsigned short* __restrict__ Qg, unsigned short* __restrict__ Kg,
    unsigned short* __restrict__ VTg)
{
    __shared__ __align__(16) unsigned short Xld[2][4096];
    __shared__ __align__(16) unsigned short Wld[2][8192];

    // id = (x%8) + 8*((y*3+z) + 12*(x/8)); bijective over 768
    const int id = blockIdx.x;
    const int xcd = id & 7;
    const int rest = id >> 3;
    const int yz = rest % 12;
    const int x_hi = rest / 12;
    const int bx = x_hi * 8 + xcd;
    const int by = yz / 3;
    const int z  = yz % 3;

    const int tileS = bx * 64;
    const int tileF = by * 128;
    const int bb0 = tileS >> 11;
    const int rl = lens[bb0 * 2], cl = lens[bb0 * 2 + 1];
    const int limit = (z == 0) ? rl : cl;
    if ((tileS & 2047) >= limit) return;       // fully padded tile: outputs unused

    const float* Xs = (z == 0) ? inQ : (z == 1) ? inK : inV;   // [4096][512] f32
    const unsigned short* W = Wbf + (size_t)z * (512 * 512);
    const float* bias = (z == 0) ? bQ : (z == 1) ? bK : bV;

    const int t = threadIdx.x;
    const int wv = t >> 6, lane = t & 63, l15 = lane & 15, quad = lane >> 4;
    const int ro = lane >> 3;                 // row within 8-row staging group
    const int lc8 = ((lane & 7) ^ ro) * 8;    // swizzled source chunk (elements)

    const float* gXf = Xs + (size_t)(tileS + wv * 16 + ro) * 512 + lc8;
    const unsigned short* gW = W + (size_t)(tileF + wv * 32 + ro) * 512 + lc8;
    const int wvo = wv * 2048;                 // W: 32 rows/wave
    const int xdst = wv * 1024 + lane * 8;     // X: 16 rows/wave, lane*16B dest

    const int f_off = (wv & 1) * 64, s_off = (wv >> 1) * 32;
    const int swk = l15 & 7;

    f32x4 acc[4][2] = {};

    // prologue: stage chunk 0 into buffer 0
    #pragma unroll
    for (int j = 0; j < 2; ++j) {
        const float* s = gXf + j * 4096;      // j*8 rows
        float4 a = *(const float4*)s;
        float4 d = *(const float4*)(s + 4);
        uint4 u;
        u.x = cvtpk(a.x, a.y); u.y = cvtpk(a.z, a.w);
        u.z = cvtpk(d.x, d.y); u.w = cvtpk(d.z, d.w);
        *(uint4*)&Xld[0][xdst + j * 512] = u;
    }
    #pragma unroll
    for (int j = 0; j < 4; ++j)
        gl_lds16(gW + j * 4096, &Wld[0][wvo + j * 512]);

    for (int kk = 0; kk < 8; ++kk) {
        __syncthreads();                       // drains W gl_lds + X ds_writes
        float4 xa[2], xd[2];
        if (kk < 7) {                          // issue prefetch for chunk kk+1
            const int k0 = (kk + 1) * 64;
            #pragma unroll
            for (int j = 0; j < 2; ++j) {
                const float* s = gXf + k0 + j * 4096;
                xa[j] = *(const float4*)s;
                xd[j] = *(const float4*)(s + 4);
            }
            #pragma unroll
            for (int j = 0; j < 4; ++j)
                gl_lds16(gW + k0 + j * 4096, &Wld[(kk + 1) & 1][wvo + j * 512]);
        }
        const unsigned short* Xb = Xld[kk & 1];
        const unsigned short* Wb = Wld[kk & 1];
        #pragma unroll
        for (int kk2 = 0; kk2 < 2; ++kk2) {
            bf16x8 wf[4], xf[2];
            #pragma unroll
            for (int i = 0; i < 4; ++i) {
                const int rw = f_off + i * 16 + l15;
                wf[i] = *(const bf16x8*)(Wb + rw * 64 + ((kk2 * 4 + quad) ^ swk) * 8);
            }
            #pragma unroll
            for (int i = 0; i < 2; ++i) {
                const int rx = s_off + i * 16 + l15;
                xf[i] = *(const bf16x8*)(Xb + rx * 64 + ((kk2 * 4 + quad) ^ swk) * 8);
            }
            #pragma unroll
            for (int ft = 0; ft < 4; ++ft)
                #pragma unroll
                for (int st = 0; st < 2; ++st)
                    acc[ft][st] = __builtin_amdgcn_mfma_f32_16x16x32_bf16(
                        wf[ft], xf[st], acc[ft][st], 0, 0, 0);
        }
        if (kk < 7) {                          // convert + write AFTER compute
            const int nb = (kk + 1) & 1;
            #pragma unroll
            for (int j = 0; j < 2; ++j) {
                uint4 u;
                u.x = cvtpk(xa[j].x, xa[j].y); u.y = cvtpk(xa[j].z, xa[j].w);
                u.z = cvtpk(xd[j].x, xd[j].y); u.w = cvtpk(xd[j].z, xd[j].w);
                *(uint4*)&Xld[nb][xdst + j * 512] = u;
            }
        }
    }

    // fold 1/sqrt(dk) AND log2(e) into Q so attention can use exp2 directly
    const float oscale = (z == 0) ? 0.18033688011112042f : 1.0f;
    #pragma unroll
    for (int ft = 0; ft < 4; ++ft) {
        const int f = tileF + f_off + ft * 16 + quad * 4;
        const int h = f >> 6, dk = f & 63;
        const float b0 = bias[f], b1 = bias[f + 1], b2 = bias[f + 2], b3 = bias[f + 3];
        #pragma unroll
        for (int st = 0; st < 2; ++st) {
            const int s = tileS + s_off + st * 16 + l15;
            const int bb = s >> 11, seq = s & 2047;
            const f32x4 a = acc[ft][st];
            if (z <= 1) {
                unsigned short* dst = ((z == 0) ? Qg : Kg)
                    + ((size_t)((bb * 8 + h) * 2048 + seq)) * 64 + dk;
                ushort4 u;
                u.x = f2bf((a[0] + b0) * oscale); u.y = f2bf((a[1] + b1) * oscale);
                u.z = f2bf((a[2] + b2) * oscale); u.w = f2bf((a[3] + b3) * oscale);
                *(ushort4*)dst = u;
            } else {
                unsigned short* dst = VTg
                    + ((size_t)((bb * 8 + h) * 64 + dk)) * 2048 + seq;
                dst[0]    = f2bf(a[0] + b0);
                dst[2048] = f2bf(a[1] + b1);
                dst[4096] = f2bf(a[2] + b2);
                dst[6144] = f2bf(a[3] + b3);
            }
        }
    }
}

// ----------------------------------------------------------- attention ------
// Flash-decoding, 4 waves split the kv loop; QBLK=32 with swapped QK^T +
// permuted K-rows (identity PV A-fragments, in-lane softmax).
// PIPELINED STAGING: each wave owns separate K (8 KB) and V (8 KB) buffers.
// Per tile: V_i issued at loop top (hidden under QK^T+softmax), K_{i+1}
// issued right after K_i's frag reads retire (hidden under softmax), one
// vmcnt(0) before PV. Removes the previously fully-exposed loop-top K wait.
__global__ __launch_bounds__(256) void attn_kernel(
    const unsigned short* __restrict__ Qg, const unsigned short* __restrict__ Kg,
    const unsigned short* __restrict__ VTg, const int* __restrict__ lens,
    unsigned short* __restrict__ AO)
{
    __shared__ __align__(16) char smem[66560];
    unsigned short* stage = (unsigned short*)smem;              // 4 x (4096+4096)
    float* Ml = (float*)(smem + 65536);                         // 128
    float* Ll = Ml + 128;                                       // 128

    const int t = threadIdx.x;
    const int wv = t >> 6, lane = t & 63, l15 = lane & 15, quad = lane >> 4;

    // id = (bh%8) + 8*(q0i + 64*(bh/8)); bijective over 1024
    const int id = blockIdx.x;
    const int xcd = id & 7;
    const int rest = id >> 3;
    const int q0i = rest % 64;
    const int bh = (rest / 64) * 8 + xcd;

    const int b = bh >> 3, h = bh & 7;
    const int q0 = q0i * 32;
    const int rl = lens[b * 2], cl = lens[b * 2 + 1];

    if (q0 >= rl) {                            // fully masked rows -> zeros
        const int row = t >> 4, cg = t & 15;
        ushort4 zz = {0, 0, 0, 0};
        #pragma unroll
        for (int rr = 0; rr < 2; ++rr)
            *(ushort4*)(AO + ((size_t)(b * 2048 + q0 + rr * 16 + row)) * 512
                        + h * 64 + cg * 4) = zz;
        return;
    }

    bf16x8 aq[2][2];
    #pragma unroll
    for (int qs = 0; qs < 2; ++qs) {
        const unsigned short* Qrow = Qg + ((size_t)(bh * 2048 + q0 + qs * 16 + l15)) * 64;
        aq[qs][0] = *(const bf16x8*)(Qrow + quad * 8);
        aq[qs][1] = *(const bf16x8*)(Qrow + 32 + quad * 8);
    }

    unsigned short* stwK = stage + wv * 8192;  // this wave's K buffer (8 KB)
    unsigned short* stwV = stwK + 4096;        // this wave's V buffer (8 KB)

    const int sro = lane >> 3;                              // staging row-in-group
    const int c0 = (((lane & 7) ^ (sro & 3)) << 3);         // staging col chunk base
    const int sk = l15 & 7;                                 // = s(g(ct,l15)), all ct
    const int sv = (l15 & 3) | ((l15 & 8) >> 1);            // = s(ct*16+l15), all ct
    const int skq0 = ((quad ^ sk) << 3), skq1 = (((quad + 4) ^ sk) << 3);
    const int svq0 = ((quad ^ sv) << 3), svq1 = (((quad + 4) ^ sv) << 3);

    f32x4 oacc[2][4] = {};
    float m_[2], l_[2];
    #pragma unroll
    for (int qs = 0; qs < 2; ++qs) { m_[qs] = -__builtin_inff(); l_[qs] = 0.f; }

    const int q_end = q0 + 32;
    const int kv_max = (cl < q_end) ? cl : q_end;
    const int ntiles = (kv_max + 63) >> 6;

    // prologue: stage first K tile (kt = wv); harmless junk if wv >= ntiles
    {
        const unsigned short* kgb = Kg + ((size_t)(bh * 2048 + wv * 64 + sro)) * 64;
        #pragma unroll
        for (int j = 0; j < 8; ++j)
            gl_lds16(kgb + j * 512 + (c0 ^ ((j & 1) << 5)), stwK + j * 512);
    }
    __builtin_amdgcn_s_waitcnt(0x0070);        // vmcnt(0)+lgkmcnt(0): K_0 staged

    for (int kt = wv; kt < ntiles; kt += 4) {
        const int kv0 = kt * 64;

        {   // issue V_i stage into stwV NOW: hides under QK^T + softmax
            const unsigned short* vgb = VTg + ((size_t)(bh * 64 + sro)) * 2048 + kv0;
            #pragma unroll
            for (int j = 0; j < 8; ++j)
                gl_lds16(vgb + j * 16384 + (c0 ^ ((j & 1) << 5)), stwV + j * 512);
        }

        f32x4 sc[2][4];
        __builtin_amdgcn_s_setprio(1);
        #pragma unroll
        for (int ct = 0; ct < 4; ++ct) {
            // permuted K-row assignment (see header comment)
            const int grow = ((l15 >> 2) << 3) + ((ct & 1) << 2) + (l15 & 3)
                           + ((ct >> 1) << 5);
            const unsigned short* krow = stwK + grow * 64;
            const bf16x8 kf0 = *(const bf16x8*)(krow + skq0);
            const bf16x8 kf1 = *(const bf16x8*)(krow + skq1);
            #pragma unroll
            for (int qs = 0; qs < 2; ++qs) {
                f32x4 zz = {};
                zz = __builtin_amdgcn_mfma_f32_16x16x32_bf16(kf0, aq[qs][0], zz, 0, 0, 0);
                sc[qs][ct] = __builtin_amdgcn_mfma_f32_16x16x32_bf16(kf1, aq[qs][1], zz, 0, 0, 0);
            }
        }
        __builtin_amdgcn_s_setprio(0);

        // K frag ds_reads retired (lgkm only — do NOT drain the V loads!)
        asm volatile("s_waitcnt lgkmcnt(0)" ::: "memory");
        if (kt + 4 < ntiles) {                 // prefetch next K tile into stwK
            const unsigned short* kgb = Kg + ((size_t)(bh * 2048 + kv0 + 256 + sro)) * 64;
            #pragma unroll
            for (int j = 0; j < 8; ++j)
                gl_lds16(kgb + j * 512 + (c0 ^ ((j & 1) << 5)), stwK + j * 512);
        }

        const bool full = (kv0 + 64 <= q0) && (kv0 + 64 <= cl) && (q_end <= rl);

        union { bf16x8 v; unsigned u[4]; } P0[2], P1[2];
        #pragma unroll
        for (int qs = 0; qs < 2; ++qs) {
            const int qme = q0 + qs * 16 + l15;    // this lane's q row
            if (!full) {
                #pragma unroll
                for (int ct = 0; ct < 4; ++ct) {
                    const int kvb = kv0 + quad * 8 + ((ct & 1) << 2) + ((ct >> 1) << 5);
                    #pragma unroll
                    for (int r = 0; r < 4; ++r) {
                        const int kv = kvb + r;
                        const bool valid = (qme < rl) && (kv < cl) && (kv <= qme);
                        sc[qs][ct][r] = valid ? sc[qs][ct][r] : -__builtin_inff();
                    }
                }
            }

            // row max: in-lane tree over 16, then butterfly across the 4 quads
            float mx = -__builtin_inff();
            #pragma unroll
            for (int ct = 0; ct < 4; ++ct)
                mx = fmaxf(mx, fmaxf(fmaxf(sc[qs][ct][0], sc[qs][ct][1]),
                                     fmaxf(sc[qs][ct][2], sc[qs][ct][3])));
            mx = fmaxf(mx, __shfl_xor(mx, 16));
            mx = fmaxf(mx, __shfl_xor(mx, 32));

            const float mnew = fmaxf(m_[qs], mx);
            const float alpha = (m_[qs] == -__builtin_inff()) ? 0.f : ex2(m_[qs] - mnew);
            const float mden = (mnew == -__builtin_inff()) ? 0.f : mnew;

            float psum = 0.f;
            #pragma unroll
            for (int ct = 0; ct < 4; ++ct) {
                #pragma unroll
                for (int r = 0; r < 4; ++r)
                    sc[qs][ct][r] = ex2(sc[qs][ct][r] - mden);
                psum += (sc[qs][ct][0] + sc[qs][ct][1]) + (sc[qs][ct][2] + sc[qs][ct][3]);
            }
            psum += __shfl_xor(psum, 16);
            psum += __shfl_xor(psum, 32);
            l_[qs] = alpha * l_[qs] + psum;
            m_[qs] = mnew;

            // redistribute alpha from q=l15 layout to oacc's q=quad*4+r rows
            const float ar0 = __shfl(alpha, quad * 4 + 0);
            const float ar1 = __shfl(alpha, quad * 4 + 1);
            const float ar2 = __shfl(alpha, quad * 4 + 2);
            const float ar3 = __shfl(alpha, quad * 4 + 3);
            #pragma unroll
            for (int ct = 0; ct < 4; ++ct) {
                oacc[qs][ct][0] *= ar0; oacc[qs][ct][1] *= ar1;
                oacc[qs][ct][2] *= ar2; oacc[qs][ct][3] *= ar3;
            }

            // pack P in-register: identity PV A-fragments, zero shuffles/LDS
            P0[qs].u[0] = cvtpk(sc[qs][0][0], sc[qs][0][1]);
            P0[qs].u[1] = cvtpk(sc[qs][0][2], sc[qs][0][3]);
            P0[qs].u[2] = cvtpk(sc[qs][1][0], sc[qs][1][1]);
            P0[qs].u[3] = cvtpk(sc[qs][1][2], sc[qs][1][3]);
            P1[qs].u[0] = cvtpk(sc[qs][2][0], sc[qs][2][1]);
            P1[qs].u[1] = cvtpk(sc[qs][2][2], sc[qs][2][3]);
            P1[qs].u[2] = cvtpk(sc[qs][3][0], sc[qs][3][1]);
            P1[qs].u[3] = cvtpk(sc[qs][3][2], sc[qs][3][3]);
        }

        // V_i staged (also drains K_{i+1}; over-wait, correctness-safe)
        __builtin_amdgcn_s_waitcnt(0x0070);
        __builtin_amdgcn_s_setprio(1);
        #pragma unroll
        for (int ct = 0; ct < 4; ++ct) {
            const unsigned short* vrow = stwV + (ct * 16 + l15) * 64;
            const bf16x8 vf0 = *(const bf16x8*)(vrow + svq0);
            const bf16x8 vf1 = *(const bf16x8*)(vrow + svq1);
            #pragma unroll
            for (int qs = 0; qs < 2; ++qs) {
                oacc[qs][ct] = __builtin_amdgcn_mfma_f32_16x16x32_bf16(P0[qs].v, vf0, oacc[qs][ct], 0, 0, 0);
                oacc[qs][ct] = __builtin_amdgcn_mfma_f32_16x16x32_bf16(P1[qs].v, vf1, oacc[qs][ct], 0, 0, 0);
            }
        }
        __builtin_amdgcn_s_setprio(0);
    }

    // publish m,l partials (separate region, safe before barrier)
    if (lane < 16) {
        #pragma unroll
        for (int qs = 0; qs < 2; ++qs) {
            Ml[wv * 32 + qs * 16 + l15] = m_[qs];
            Ll[wv * 32 + qs * 16 + l15] = l_[qs];
        }
    }
    __syncthreads();                           // all waves done with staging

    // O partials alias the staging region (stride 68 floats: 2-way only)
    float* Po = (float*)smem;
    #pragma unroll
    for (int qs = 0; qs < 2; ++qs)
        #pragma unroll
        for (int ct = 0; ct < 4; ++ct)
            #pragma unroll
            for (int r = 0; r < 4; ++r)
                Po[wv * 2176 + (qs * 16 + quad * 4 + r) * 68 + ct * 16 + l15] = oacc[qs][ct][r];
    __syncthreads();

    // merge 4 partials; each thread handles 2 of the 32 rows
    const int row = t >> 4, cg = t & 15;
    #pragma unroll
    for (int rr = 0; rr < 2; ++rr) {
        const int orow = rr * 16 + row;
        float mw[4];
        float mstar = -__builtin_inff();
        #pragma unroll
        for (int w = 0; w < 4; ++w) {
            mw[w] = Ml[w * 32 + orow];
            mstar = fmaxf(mstar, mw[w]);
        }
        f32x4 o = {};
        if (mstar != -__builtin_inff()) {
            float lst = 0.f;
            #pragma unroll
            for (int w = 0; w < 4; ++w) {
                const float sw = (mw[w] == -__builtin_inff()) ? 0.f : ex2(mw[w] - mstar);
                lst += sw * Ll[w * 32 + orow];
                const f32x4 pv = *(const f32x4*)&Po[w * 2176 + orow * 68 + cg * 4];
                o[0] += sw * pv[0]; o[1] += sw * pv[1];
                o[2] += sw * pv[2]; o[3] += sw * pv[3];
            }
            const float inv = (lst > 0.f) ? 1.f / lst : 0.f;
            o[0] *= inv; o[1] *= inv; o[2] *= inv; o[3] *= inv;
        }
        ushort4 u;
        u.x = f2bf(o[0]); u.y = f2bf(o[1]); u.z = f2bf(o[2]); u.w = f2bf(o[3]);
        *(ushort4*)(AO + ((size_t)(b * 2048 + q0 + orow)) * 512 + h * 64 + cg * 4) = u;
    }
}

// ------------------------------------------------------------- output GEMM --
// BM=64 x BN=128 tiles, 256 blocks = 1/CU, XCD-locality decode.
__global__ __launch_bounds__(256) void out_gemm(
    const unsigned short* __restrict__ AO, const unsigned short* __restrict__ Wbf,
    const float* __restrict__ bO, const int* __restrict__ lens, float* __restrict__ out)
{
    __shared__ __align__(16) unsigned short Xld[2][4096];
    __shared__ __align__(16) unsigned short Wld[2][8192];

    // id = (x%8) + 8*(y + 4*(x/8)); bijective over 256
    const int id = blockIdx.x;
    const int xcd = id & 7;
    const int rest = id >> 3;
    const int by = rest % 4;
    const int bx = (rest / 4) * 8 + xcd;

    const int tileS = bx * 64;
    const int tileF = by * 128;
    const int bb0 = tileS >> 11;
    const int rl = lens[bb0 * 2];
    const int t = threadIdx.x;

    if ((tileS & 2047) >= rl) {                // padded rows: out = bias
        const int r0 = t >> 2;
        const int cg = (t & 3) * 32;
        float4 bv[8];
        #pragma unroll
        for (int j = 0; j < 8; ++j) bv[j] = *(const float4*)(bO + tileF + cg + j * 4);
        float* orow = out + (size_t)(tileS + r0) * 512 + tileF + cg;
        #pragma unroll
        for (int j = 0; j < 8; ++j) *(float4*)(orow + j * 4) = bv[j];
        return;
    }

    const unsigned short* W = Wbf + (size_t)3 * (512 * 512);
    const int wv = t >> 6, lane = t & 63, l15 = lane & 15, quad = lane >> 4;
    const int ro = lane >> 3;
    const int lc8 = ((lane & 7) ^ ro) * 8;

    const unsigned short* gX = AO + (size_t)(tileS + wv * 16 + ro) * 512 + lc8;
    const unsigned short* gW = W + (size_t)(tileF + wv * 32 + ro) * 512 + lc8;
    const int xvo = wv * 1024;                 // X: 16 rows/wave
    const int wvo = wv * 2048;                 // W: 32 rows/wave

    const int f_off = (wv & 1) * 64, s_off = (wv >> 1) * 32;
    const int swk = l15 & 7;

    f32x4 acc[4][2] = {};

    #pragma unroll
    for (int j = 0; j < 2; ++j)
        gl_lds16(gX + j * 4096, &Xld[0][xvo + j * 512]);
    #pragma unroll
    for (int j = 0; j < 4; ++j)
        gl_lds16(gW + j * 4096, &Wld[0][wvo + j * 512]);

    for (int kk = 0; kk < 8; ++kk) {
        __syncthreads();
        if (kk < 7) {
            const int k0 = (kk + 1) * 64;
            const int nb = (kk + 1) & 1;
            #pragma unroll
            for (int j = 0; j < 2; ++j)
                gl_lds16(gX + k0 + j * 4096, &Xld[nb][xvo + j * 512]);
            #pragma unroll
            for (int j = 0; j < 4; ++j)
                gl_lds16(gW + k0 + j * 4096, &Wld[nb][wvo + j * 512]);
        }
        const unsigned short* Xb = Xld[kk & 1];
        const unsigned short* Wb = Wld[kk & 1];
        #pragma unroll
        for (int kk2 = 0; kk2 < 2; ++kk2) {
            bf16x8 wf[4], xf[2];
            #pragma unroll
            for (int i = 0; i < 4; ++i) {
                const int rw = f_off + i * 16 + l15;
                wf[i] = *(const bf16x8*)(Wb + rw * 64 + ((kk2 * 4 + quad) ^ swk) * 8);
            }
            #pragma unroll
            for (int i = 0; i < 2; ++i) {
                const int rx = s_off + i * 16 + l15;
                xf[i] = *(const bf16x8*)(Xb + rx * 64 + ((kk2 * 4 + quad) ^ swk) * 8);
            }
            #pragma unroll
            for (int ft = 0; ft < 4; ++ft)
                #pragma unroll
                for (int st = 0; st < 2; ++st)
                    acc[ft][st] = __builtin_amdgcn_mfma_f32_16x16x32_bf16(
                        wf[ft], xf[st], acc[ft][st], 0, 0, 0);
        }
    }

    #pragma unroll
    for (int ft = 0; ft < 4; ++ft) {
        const int f = tileF + f_off + ft * 16 + quad * 4;
        const float4 bv = *(const float4*)(bO + f);
        #pragma unroll
        for (int st = 0; st < 2; ++st) {
            const int s = tileS + s_off + st * 16 + l15;
            float4 o;
            o.x = acc[ft][st][0] + bv.x;
            o.y = acc[ft][st][1] + bv.y;
            o.z = acc[ft][st][2] + bv.z;
            o.w = acc[ft][st][3] + bv.w;
            *(float4*)(out + (size_t)s * 512 + f) = o;
        }
    }
}

// -------------------------------------------------------------- launch ------
extern "C" void kernel_launch(void* const* d_in, const int* in_sizes, int n_in,
                              void* d_out, int out_size, void* d_ws, size_t ws_size,
                              hipStream_t stream)
{
    const float* inQ = (const float*)d_in[0];
    const float* inK = (const float*)d_in[1];
    const float* inV = (const float*)d_in[2];
    const int*   rpm = (const int*)d_in[3];
    const int*   cpm = (const int*)d_in[4];
    const float* WQ  = (const float*)d_in[5];
    const float* bQ  = (const float*)d_in[6];
    const float* WK  = (const float*)d_in[7];
    const float* bK  = (const float*)d_in[8];
    const float* WV  = (const float*)d_in[9];
    const float* bV  = (const float*)d_in[10];
    const float* WO  = (const float*)d_in[11];
    const float* bO  = (const float*)d_in[12];
    float* out = (float*)d_out;

    char* ws = (char*)d_ws;
    unsigned short* Wbf = (unsigned short*)(ws + 12582912);      //  2 MB
    unsigned short* Qg  = (unsigned short*)(ws + 14680064);      //  4 MB
    unsigned short* Kg  = (unsigned short*)(ws + 18874368);      //  4 MB
    unsigned short* VTg = (unsigned short*)(ws + 23068672);      //  4 MB
    unsigned short* AO  = (unsigned short*)(ws + 27262976);      //  4 MB
    int* lens           = (int*)(ws + 31457280);

    cvtlens_kernel<<<dim3(512), dim3(256), 0, stream>>>(
        WQ, WK, WV, WO, rpm, cpm, Wbf, lens);
    proj_gemm<<<dim3(768), dim3(256), 0, stream>>>(
        inQ, inK, inV, Wbf, bQ, bK, bV, lens, Qg, Kg, VTg);
    attn_kernel<<<dim3(1024), dim3(256), 0, stream>>>(Qg, Kg, VTg, lens, AO);
    out_gemm<<<dim3(256), dim3(256), 0, stream>>>(AO, Wbf, bO, lens, out);
}

// Round 17
// 133.370 us; speedup vs baseline: 1.0321x; 1.0137x over previous
//
#include <hip/hip_runtime.h>

#define S_LEN 2048
#define D_MODEL 512
#define NHEAD 8
#define BATCH 2

typedef __attribute__((ext_vector_type(8))) short bf16x8;
typedef __attribute__((ext_vector_type(4))) float f32x4;

__device__ __forceinline__ unsigned short f2bf(float f) {
    union { float f; unsigned u; } v; v.f = f;
    unsigned u = v.u + 0x7FFFu + ((v.u >> 16) & 1u);   // RNE
    return (unsigned short)(u >> 16);
}

// 2^x via v_exp_f32 (native). exp2(-inf)=0 in HW, which the masking relies on.
__device__ __forceinline__ float ex2(float x) {
    return __builtin_amdgcn_exp2f(x);
}

// pack two f32 -> two bf16 in one dword (RNE), 1 instr vs ~12 ALU ops
__device__ __forceinline__ unsigned cvtpk(float lo, float hi) {
    unsigned r;
    asm("v_cvt_pk_bf16_f32 %0, %1, %2" : "=v"(r) : "v"(lo), "v"(hi));
    return r;
}

// async global->LDS, 16B per lane, LDS dest = wave-uniform base + lane*16
__device__ __forceinline__ void gl_lds16(const unsigned short* g, unsigned short* l) {
    __builtin_amdgcn_global_load_lds(
        (const __attribute__((address_space(1))) void*)g,
        (__attribute__((address_space(3))) void*)l,
        16, 0, 0);
}

// --------------------------------------------- lens + W fp32->bf16 convert --
__global__ __launch_bounds__(256) void cvtlens_kernel(
    const float* __restrict__ WQ, const float* __restrict__ WK,
    const float* __restrict__ WV, const float* __restrict__ WO,
    const int* __restrict__ rpm, const int* __restrict__ cpm,
    unsigned short* __restrict__ Wbf, int* __restrict__ lens)
{
    const int t = threadIdx.x;
    if (blockIdx.x < 2) {
        __shared__ int red[256];
        const int b = blockIdx.x;
        int sr = 0, sc2 = 0;
        for (int i = t; i < S_LEN; i += 256) {
            sr  += rpm[b * S_LEN + i];
            sc2 += cpm[b * S_LEN + i];
        }
        red[t] = sr;
        __syncthreads();
        for (int off = 128; off > 0; off >>= 1) {
            if (t < off) red[t] += red[t + off];
            __syncthreads();
        }
        if (t == 0) lens[b * 2 + 0] = red[0];
        __syncthreads();
        red[t] = sc2;
        __syncthreads();
        for (int off = 128; off > 0; off >>= 1) {
            if (t < off) red[t] += red[t + off];
            __syncthreads();
        }
        if (t == 0) lens[b * 2 + 1] = red[0];
    }

    const int NW = 131072;           // 4*512*512/8 chunks
    const int stride = gridDim.x * 256;
    for (int c = blockIdx.x * 256 + t; c < NW; c += stride) {
        const int wflat = c << 3;
        const int wz = wflat >> 18;
        const int off = wflat & 262143;
        const float* src = ((wz == 0) ? WQ : (wz == 1) ? WK : (wz == 2) ? WV : WO) + off;
        float4 a = *(const float4*)src;
        float4 d = *(const float4*)(src + 4);
        unsigned short* w = Wbf + wflat;
        w[0] = f2bf(a.x); w[1] = f2bf(a.y); w[2] = f2bf(a.z); w[3] = f2bf(a.w);
        w[4] = f2bf(d.x); w[5] = f2bf(d.y); w[6] = f2bf(d.z); w[7] = f2bf(d.w);
    }
}

// --------------------------------------------------------- projection GEMM --
// BM=64 x BN=128 tiles, BK=64, double-buffered, 768 blocks = 3/CU (48 KB).
// 1D grid with XCD-locality decode.
__global__ __launch_bounds__(256) void proj_gemm(
    const float* __restrict__ inQ, const float* __restrict__ inK,
    const float* __restrict__ inV, const unsigned short* __restrict__ Wbf,
    const float* __restrict__ bQ, const float* __restrict__ bK, const float* __restrict__ bV,
    const int* __restrict__ lens,
    unsigned short* __restrict__ Qg, unsigned short* __restrict__ Kg,
    unsigned short* __restrict__ VTg)
{
    __shared__ __align__(16) unsigned short Xld[2][4096];
    __shared__ __align__(16) unsigned short Wld[2][8192];

    // id = (x%8) + 8*((y*3+z) + 12*(x/8)); bijective over 768
    const int id = blockIdx.x;
    const int xcd = id & 7;
    const int rest = id >> 3;
    const int yz = rest % 12;
    const int x_hi = rest / 12;
    const int bx = x_hi * 8 + xcd;
    const int by = yz / 3;
    const int z  = yz % 3;

    const int tileS = bx * 64;
    const int tileF = by * 128;
    const int bb0 = tileS >> 11;
    const int rl = lens[bb0 * 2], cl = lens[bb0 * 2 + 1];
    const int limit = (z == 0) ? rl : cl;
    if ((tileS & 2047) >= limit) return;       // fully padded tile: outputs unused

    const float* Xs = (z == 0) ? inQ : (z == 1) ? inK : inV;   // [4096][512] f32
    const unsigned short* W = Wbf + (size_t)z * (512 * 512);
    const float* bias = (z == 0) ? bQ : (z == 1) ? bK : bV;

    const int t = threadIdx.x;
    const int wv = t >> 6, lane = t & 63, l15 = lane & 15, quad = lane >> 4;
    const int ro = lane >> 3;                 // row within 8-row staging group
    const int lc8 = ((lane & 7) ^ ro) * 8;    // swizzled source chunk (elements)

    const float* gXf = Xs + (size_t)(tileS + wv * 16 + ro) * 512 + lc8;
    const unsigned short* gW = W + (size_t)(tileF + wv * 32 + ro) * 512 + lc8;
    const int wvo = wv * 2048;                 // W: 32 rows/wave
    const int xdst = wv * 1024 + lane * 8;     // X: 16 rows/wave, lane*16B dest

    const int f_off = (wv & 1) * 64, s_off = (wv >> 1) * 32;
    const int swk = l15 & 7;

    f32x4 acc[4][2] = {};

    // prologue: stage chunk 0 into buffer 0
    #pragma unroll
    for (int j = 0; j < 2; ++j) {
        const float* s = gXf + j * 4096;      // j*8 rows
        float4 a = *(const float4*)s;
        float4 d = *(const float4*)(s + 4);
        uint4 u;
        u.x = cvtpk(a.x, a.y); u.y = cvtpk(a.z, a.w);
        u.z = cvtpk(d.x, d.y); u.w = cvtpk(d.z, d.w);
        *(uint4*)&Xld[0][xdst + j * 512] = u;
    }
    #pragma unroll
    for (int j = 0; j < 4; ++j)
        gl_lds16(gW + j * 4096, &Wld[0][wvo + j * 512]);

    for (int kk = 0; kk < 8; ++kk) {
        __syncthreads();                       // drains W gl_lds + X ds_writes
        float4 xa[2], xd[2];
        if (kk < 7) {                          // issue prefetch for chunk kk+1
            const int k0 = (kk + 1) * 64;
            #pragma unroll
            for (int j = 0; j < 2; ++j) {
                const float* s = gXf + k0 + j * 4096;
                xa[j] = *(const float4*)s;
                xd[j] = *(const float4*)(s + 4);
            }
            #pragma unroll
            for (int j = 0; j < 4; ++j)
                gl_lds16(gW + k0 + j * 4096, &Wld[(kk + 1) & 1][wvo + j * 512]);
        }
        const unsigned short* Xb = Xld[kk & 1];
        const unsigned short* Wb = Wld[kk & 1];
        #pragma unroll
        for (int kk2 = 0; kk2 < 2; ++kk2) {
            bf16x8 wf[4], xf[2];
            #pragma unroll
            for (int i = 0; i < 4; ++i) {
                const int rw = f_off + i * 16 + l15;
                wf[i] = *(const bf16x8*)(Wb + rw * 64 + ((kk2 * 4 + quad) ^ swk) * 8);
            }
            #pragma unroll
            for (int i = 0; i < 2; ++i) {
                const int rx = s_off + i * 16 + l15;
                xf[i] = *(const bf16x8*)(Xb + rx * 64 + ((kk2 * 4 + quad) ^ swk) * 8);
            }
            #pragma unroll
            for (int ft = 0; ft < 4; ++ft)
                #pragma unroll
                for (int st = 0; st < 2; ++st)
                    acc[ft][st] = __builtin_amdgcn_mfma_f32_16x16x32_bf16(
                        wf[ft], xf[st], acc[ft][st], 0, 0, 0);
        }
        if (kk < 7) {                          // convert + write AFTER compute
            const int nb = (kk + 1) & 1;
            #pragma unroll
            for (int j = 0; j < 2; ++j) {
                uint4 u;
                u.x = cvtpk(xa[j].x, xa[j].y); u.y = cvtpk(xa[j].z, xa[j].w);
                u.z = cvtpk(xd[j].x, xd[j].y); u.w = cvtpk(xd[j].z, xd[j].w);
                *(uint4*)&Xld[nb][xdst + j * 512] = u;
            }
        }
    }

    // fold 1/sqrt(dk) AND log2(e) into Q so attention can use exp2 directly
    const float oscale = (z == 0) ? 0.18033688011112042f : 1.0f;
    #pragma unroll
    for (int ft = 0; ft < 4; ++ft) {
        const int f = tileF + f_off + ft * 16 + quad * 4;
        const int h = f >> 6, dk = f & 63;
        const float b0 = bias[f], b1 = bias[f + 1], b2 = bias[f + 2], b3 = bias[f + 3];
        #pragma unroll
        for (int st = 0; st < 2; ++st) {
            const int s = tileS + s_off + st * 16 + l15;
            const int bb = s >> 11, seq = s & 2047;
            const f32x4 a = acc[ft][st];
            if (z <= 1) {
                unsigned short* dst = ((z == 0) ? Qg : Kg)
                    + ((size_t)((bb * 8 + h) * 2048 + seq)) * 64 + dk;
                ushort4 u;
                u.x = f2bf((a[0] + b0) * oscale); u.y = f2bf((a[1] + b1) * oscale);
                u.z = f2bf((a[2] + b2) * oscale); u.w = f2bf((a[3] + b3) * oscale);
                *(ushort4*)dst = u;
            } else {
                unsigned short* dst = VTg
                    + ((size_t)((bb * 8 + h) * 64 + dk)) * 2048 + seq;
                dst[0]    = f2bf(a[0] + b0);
                dst[2048] = f2bf(a[1] + b1);
                dst[4096] = f2bf(a[2] + b2);
                dst[6144] = f2bf(a[3] + b3);
            }
        }
    }
}

// ----------------------------------------------------------- attention ------
// Flash-decoding, 4 waves split the kv loop; QBLK=32 with swapped QK^T +
// permuted K-rows (identity PV A-fragments, in-lane softmax). Pipelined
// K/V staging (separate 8 KB buffers/wave, K prefetched across iterations).
// LPT DISPATCH: q0i decoded in DESCENDING order — causal masking makes work
// grow ~linearly with q0, and with 2 blocks/CU resident + greedy backfill,
// heaviest-first removes the long-tail makespan of ascending order.
__global__ __launch_bounds__(256) void attn_kernel(
    const unsigned short* __restrict__ Qg, const unsigned short* __restrict__ Kg,
    const unsigned short* __restrict__ VTg, const int* __restrict__ lens,
    unsigned short* __restrict__ AO)
{
    __shared__ __align__(16) char smem[66560];
    unsigned short* stage = (unsigned short*)smem;              // 4 x (4096+4096)
    float* Ml = (float*)(smem + 65536);                         // 128
    float* Ll = Ml + 128;                                       // 128

    const int t = threadIdx.x;
    const int wv = t >> 6, lane = t & 63, l15 = lane & 15, quad = lane >> 4;

    // id = (bh%8) + 8*((63-q0i) + 64*(bh/8)); bijective over 1024; LPT order
    const int id = blockIdx.x;
    const int xcd = id & 7;
    const int rest = id >> 3;
    const int q0i = 63 - (rest % 64);
    const int bh = (rest / 64) * 8 + xcd;

    const int b = bh >> 3, h = bh & 7;
    const int q0 = q0i * 32;
    const int rl = lens[b * 2], cl = lens[b * 2 + 1];

    if (q0 >= rl) {                            // fully masked rows -> zeros
        const int row = t >> 4, cg = t & 15;
        ushort4 zz = {0, 0, 0, 0};
        #pragma unroll
        for (int rr = 0; rr < 2; ++rr)
            *(ushort4*)(AO + ((size_t)(b * 2048 + q0 + rr * 16 + row)) * 512
                        + h * 64 + cg * 4) = zz;
        return;
    }

    bf16x8 aq[2][2];
    #pragma unroll
    for (int qs = 0; qs < 2; ++qs) {
        const unsigned short* Qrow = Qg + ((size_t)(bh * 2048 + q0 + qs * 16 + l15)) * 64;
        aq[qs][0] = *(const bf16x8*)(Qrow + quad * 8);
        aq[qs][1] = *(const bf16x8*)(Qrow + 32 + quad * 8);
    }

    unsigned short* stwK = stage + wv * 8192;  // this wave's K buffer (8 KB)
    unsigned short* stwV = stwK + 4096;        // this wave's V buffer (8 KB)

    const int sro = lane >> 3;                              // staging row-in-group
    const int c0 = (((lane & 7) ^ (sro & 3)) << 3);         // staging col chunk base
    const int sk = l15 & 7;                                 // = s(g(ct,l15)), all ct
    const int sv = (l15 & 3) | ((l15 & 8) >> 1);            // = s(ct*16+l15), all ct
    const int skq0 = ((quad ^ sk) << 3), skq1 = (((quad + 4) ^ sk) << 3);
    const int svq0 = ((quad ^ sv) << 3), svq1 = (((quad + 4) ^ sv) << 3);

    f32x4 oacc[2][4] = {};
    float m_[2], l_[2];
    #pragma unroll
    for (int qs = 0; qs < 2; ++qs) { m_[qs] = -__builtin_inff(); l_[qs] = 0.f; }

    const int q_end = q0 + 32;
    const int kv_max = (cl < q_end) ? cl : q_end;
    const int ntiles = (kv_max + 63) >> 6;

    // prologue: stage first K tile (kt = wv); harmless junk if wv >= ntiles
    {
        const unsigned short* kgb = Kg + ((size_t)(bh * 2048 + wv * 64 + sro)) * 64;
        #pragma unroll
        for (int j = 0; j < 8; ++j)
            gl_lds16(kgb + j * 512 + (c0 ^ ((j & 1) << 5)), stwK + j * 512);
    }
    __builtin_amdgcn_s_waitcnt(0x0070);        // vmcnt(0)+lgkmcnt(0): K_0 staged

    for (int kt = wv; kt < ntiles; kt += 4) {
        const int kv0 = kt * 64;

        {   // issue V_i stage into stwV NOW: hides under QK^T + softmax
            const unsigned short* vgb = VTg + ((size_t)(bh * 64 + sro)) * 2048 + kv0;
            #pragma unroll
            for (int j = 0; j < 8; ++j)
                gl_lds16(vgb + j * 16384 + (c0 ^ ((j & 1) << 5)), stwV + j * 512);
        }

        f32x4 sc[2][4];
        __builtin_amdgcn_s_setprio(1);
        #pragma unroll
        for (int ct = 0; ct < 4; ++ct) {
            // permuted K-row assignment (see header comment)
            const int grow = ((l15 >> 2) << 3) + ((ct & 1) << 2) + (l15 & 3)
                           + ((ct >> 1) << 5);
            const unsigned short* krow = stwK + grow * 64;
            const bf16x8 kf0 = *(const bf16x8*)(krow + skq0);
            const bf16x8 kf1 = *(const bf16x8*)(krow + skq1);
            #pragma unroll
            for (int qs = 0; qs < 2; ++qs) {
                f32x4 zz = {};
                zz = __builtin_amdgcn_mfma_f32_16x16x32_bf16(kf0, aq[qs][0], zz, 0, 0, 0);
                sc[qs][ct] = __builtin_amdgcn_mfma_f32_16x16x32_bf16(kf1, aq[qs][1], zz, 0, 0, 0);
            }
        }
        __builtin_amdgcn_s_setprio(0);

        // K frag ds_reads retired (lgkm only — do NOT drain the V loads!)
        asm volatile("s_waitcnt lgkmcnt(0)" ::: "memory");
        if (kt + 4 < ntiles) {                 // prefetch next K tile into stwK
            const unsigned short* kgb = Kg + ((size_t)(bh * 2048 + kv0 + 256 + sro)) * 64;
            #pragma unroll
            for (int j = 0; j < 8; ++j)
                gl_lds16(kgb + j * 512 + (c0 ^ ((j & 1) << 5)), stwK + j * 512);
        }

        const bool full = (kv0 + 64 <= q0) && (kv0 + 64 <= cl) && (q_end <= rl);

        union { bf16x8 v; unsigned u[4]; } P0[2], P1[2];
        #pragma unroll
        for (int qs = 0; qs < 2; ++qs) {
            const int qme = q0 + qs * 16 + l15;    // this lane's q row
            if (!full) {
                #pragma unroll
                for (int ct = 0; ct < 4; ++ct) {
                    const int kvb = kv0 + quad * 8 + ((ct & 1) << 2) + ((ct >> 1) << 5);
                    #pragma unroll
                    for (int r = 0; r < 4; ++r) {
                        const int kv = kvb + r;
                        const bool valid = (qme < rl) && (kv < cl) && (kv <= qme);
                        sc[qs][ct][r] = valid ? sc[qs][ct][r] : -__builtin_inff();
                    }
                }
            }

            // row max: in-lane tree over 16, then butterfly across the 4 quads
            float mx = -__builtin_inff();
            #pragma unroll
            for (int ct = 0; ct < 4; ++ct)
                mx = fmaxf(mx, fmaxf(fmaxf(sc[qs][ct][0], sc[qs][ct][1]),
                                     fmaxf(sc[qs][ct][2], sc[qs][ct][3])));
            mx = fmaxf(mx, __shfl_xor(mx, 16));
            mx = fmaxf(mx, __shfl_xor(mx, 32));

            const float mnew = fmaxf(m_[qs], mx);
            const float alpha = (m_[qs] == -__builtin_inff()) ? 0.f : ex2(m_[qs] - mnew);
            const float mden = (mnew == -__builtin_inff()) ? 0.f : mnew;

            float psum = 0.f;
            #pragma unroll
            for (int ct = 0; ct < 4; ++ct) {
                #pragma unroll
                for (int r = 0; r < 4; ++r)
                    sc[qs][ct][r] = ex2(sc[qs][ct][r] - mden);
                psum += (sc[qs][ct][0] + sc[qs][ct][1]) + (sc[qs][ct][2] + sc[qs][ct][3]);
            }
            psum += __shfl_xor(psum, 16);
            psum += __shfl_xor(psum, 32);
            l_[qs] = alpha * l_[qs] + psum;
            m_[qs] = mnew;

            // redistribute alpha from q=l15 layout to oacc's q=quad*4+r rows
            const float ar0 = __shfl(alpha, quad * 4 + 0);
            const float ar1 = __shfl(alpha, quad * 4 + 1);
            const float ar2 = __shfl(alpha, quad * 4 + 2);
            const float ar3 = __shfl(alpha, quad * 4 + 3);
            #pragma unroll
            for (int ct = 0; ct < 4; ++ct) {
                oacc[qs][ct][0] *= ar0; oacc[qs][ct][1] *= ar1;
                oacc[qs][ct][2] *= ar2; oacc[qs][ct][3] *= ar3;
            }

            // pack P in-register: identity PV A-fragments, zero shuffles/LDS
            P0[qs].u[0] = cvtpk(sc[qs][0][0], sc[qs][0][1]);
            P0[qs].u[1] = cvtpk(sc[qs][0][2], sc[qs][0][3]);
            P0[qs].u[2] = cvtpk(sc[qs][1][0], sc[qs][1][1]);
            P0[qs].u[3] = cvtpk(sc[qs][1][2], sc[qs][1][3]);
            P1[qs].u[0] = cvtpk(sc[qs][2][0], sc[qs][2][1]);
            P1[qs].u[1] = cvtpk(sc[qs][2][2], sc[qs][2][3]);
            P1[qs].u[2] = cvtpk(sc[qs][3][0], sc[qs][3][1]);
            P1[qs].u[3] = cvtpk(sc[qs][3][2], sc[qs][3][3]);
        }

        // V_i staged (also drains K_{i+1}; over-wait, correctness-safe)
        __builtin_amdgcn_s_waitcnt(0x0070);
        __builtin_amdgcn_s_setprio(1);
        #pragma unroll
        for (int ct = 0; ct < 4; ++ct) {
            const unsigned short* vrow = stwV + (ct * 16 + l15) * 64;
            const bf16x8 vf0 = *(const bf16x8*)(vrow + svq0);
            const bf16x8 vf1 = *(const bf16x8*)(vrow + svq1);
            #pragma unroll
            for (int qs = 0; qs < 2; ++qs) {
                oacc[qs][ct] = __builtin_amdgcn_mfma_f32_16x16x32_bf16(P0[qs].v, vf0, oacc[qs][ct], 0, 0, 0);
                oacc[qs][ct] = __builtin_amdgcn_mfma_f32_16x16x32_bf16(P1[qs].v, vf1, oacc[qs][ct], 0, 0, 0);
            }
        }
        __builtin_amdgcn_s_setprio(0);
    }

    // publish m,l partials (separate region, safe before barrier)
    if (lane < 16) {
        #pragma unroll
        for (int qs = 0; qs < 2; ++qs) {
            Ml[wv * 32 + qs * 16 + l15] = m_[qs];
            Ll[wv * 32 + qs * 16 + l15] = l_[qs];
        }
    }
    __syncthreads();                           // all waves done with staging

    // O partials alias the staging region (stride 68 floats: 2-way only)
    float* Po = (float*)smem;
    #pragma unroll
    for (int qs = 0; qs < 2; ++qs)
        #pragma unroll
        for (int ct = 0; ct < 4; ++ct)
            #pragma unroll
            for (int r = 0; r < 4; ++r)
                Po[wv * 2176 + (qs * 16 + quad * 4 + r) * 68 + ct * 16 + l15] = oacc[qs][ct][r];
    __syncthreads();

    // merge 4 partials; each thread handles 2 of the 32 rows
    const int row = t >> 4, cg = t & 15;
    #pragma unroll
    for (int rr = 0; rr < 2; ++rr) {
        const int orow = rr * 16 + row;
        float mw[4];
        float mstar = -__builtin_inff();
        #pragma unroll
        for (int w = 0; w < 4; ++w) {
            mw[w] = Ml[w * 32 + orow];
            mstar = fmaxf(mstar, mw[w]);
        }
        f32x4 o = {};
        if (mstar != -__builtin_inff()) {
            float lst = 0.f;
            #pragma unroll
            for (int w = 0; w < 4; ++w) {
                const float sw = (mw[w] == -__builtin_inff()) ? 0.f : ex2(mw[w] - mstar);
                lst += sw * Ll[w * 32 + orow];
                const f32x4 pv = *(const f32x4*)&Po[w * 2176 + orow * 68 + cg * 4];
                o[0] += sw * pv[0]; o[1] += sw * pv[1];
                o[2] += sw * pv[2]; o[3] += sw * pv[3];
            }
            const float inv = (lst > 0.f) ? 1.f / lst : 0.f;
            o[0] *= inv; o[1] *= inv; o[2] *= inv; o[3] *= inv;
        }
        ushort4 u;
        u.x = f2bf(o[0]); u.y = f2bf(o[1]); u.z = f2bf(o[2]); u.w = f2bf(o[3]);
        *(ushort4*)(AO + ((size_t)(b * 2048 + q0 + orow)) * 512 + h * 64 + cg * 4) = u;
    }
}

// ------------------------------------------------------------- output GEMM --
// BM=64 x BN=128 tiles, 256 blocks = 1/CU, XCD-locality decode.
__global__ __launch_bounds__(256) void out_gemm(
    const unsigned short* __restrict__ AO, const unsigned short* __restrict__ Wbf,
    const float* __restrict__ bO, const int* __restrict__ lens, float* __restrict__ out)
{
    __shared__ __align__(16) unsigned short Xld[2][4096];
    __shared__ __align__(16) unsigned short Wld[2][8192];

    // id = (x%8) + 8*(y + 4*(x/8)); bijective over 256
    const int id = blockIdx.x;
    const int xcd = id & 7;
    const int rest = id >> 3;
    const int by = rest % 4;
    const int bx = (rest / 4) * 8 + xcd;

    const int tileS = bx * 64;
    const int tileF = by * 128;
    const int bb0 = tileS >> 11;
    const int rl = lens[bb0 * 2];
    const int t = threadIdx.x;

    if ((tileS & 2047) >= rl) {                // padded rows: out = bias
        const int r0 = t >> 2;
        const int cg = (t & 3) * 32;
        float4 bv[8];
        #pragma unroll
        for (int j = 0; j < 8; ++j) bv[j] = *(const float4*)(bO + tileF + cg + j * 4);
        float* orow = out + (size_t)(tileS + r0) * 512 + tileF + cg;
        #pragma unroll
        for (int j = 0; j < 8; ++j) *(float4*)(orow + j * 4) = bv[j];
        return;
    }

    const unsigned short* W = Wbf + (size_t)3 * (512 * 512);
    const int wv = t >> 6, lane = t & 63, l15 = lane & 15, quad = lane >> 4;
    const int ro = lane >> 3;
    const int lc8 = ((lane & 7) ^ ro) * 8;

    const unsigned short* gX = AO + (size_t)(tileS + wv * 16 + ro) * 512 + lc8;
    const unsigned short* gW = W + (size_t)(tileF + wv * 32 + ro) * 512 + lc8;
    const int xvo = wv * 1024;                 // X: 16 rows/wave
    const int wvo = wv * 2048;                 // W: 32 rows/wave

    const int f_off = (wv & 1) * 64, s_off = (wv >> 1) * 32;
    const int swk = l15 & 7;

    f32x4 acc[4][2] = {};

    #pragma unroll
    for (int j = 0; j < 2; ++j)
        gl_lds16(gX + j * 4096, &Xld[0][xvo + j * 512]);
    #pragma unroll
    for (int j = 0; j < 4; ++j)
        gl_lds16(gW + j * 4096, &Wld[0][wvo + j * 512]);

    for (int kk = 0; kk < 8; ++kk) {
        __syncthreads();
        if (kk < 7) {
            const int k0 = (kk + 1) * 64;
            const int nb = (kk + 1) & 1;
            #pragma unroll
            for (int j = 0; j < 2; ++j)
                gl_lds16(gX + k0 + j * 4096, &Xld[nb][xvo + j * 512]);
            #pragma unroll
            for (int j = 0; j < 4; ++j)
                gl_lds16(gW + k0 + j * 4096, &Wld[nb][wvo + j * 512]);
        }
        const unsigned short* Xb = Xld[kk & 1];
        const unsigned short* Wb = Wld[kk & 1];
        #pragma unroll
        for (int kk2 = 0; kk2 < 2; ++kk2) {
            bf16x8 wf[4], xf[2];
            #pragma unroll
            for (int i = 0; i < 4; ++i) {
                const int rw = f_off + i * 16 + l15;
                wf[i] = *(const bf16x8*)(Wb + rw * 64 + ((kk2 * 4 + quad) ^ swk) * 8);
            }
            #pragma unroll
            for (int i = 0; i < 2; ++i) {
                const int rx = s_off + i * 16 + l15;
                xf[i] = *(const bf16x8*)(Xb + rx * 64 + ((kk2 * 4 + quad) ^ swk) * 8);
            }
            #pragma unroll
            for (int ft = 0; ft < 4; ++ft)
                #pragma unroll
                for (int st = 0; st < 2; ++st)
                    acc[ft][st] = __builtin_amdgcn_mfma_f32_16x16x32_bf16(
                        wf[ft], xf[st], acc[ft][st], 0, 0, 0);
        }
    }

    #pragma unroll
    for (int ft = 0; ft < 4; ++ft) {
        const int f = tileF + f_off + ft * 16 + quad * 4;
        const float4 bv = *(const float4*)(bO + f);
        #pragma unroll
        for (int st = 0; st < 2; ++st) {
            const int s = tileS + s_off + st * 16 + l15;
            float4 o;
            o.x = acc[ft][st][0] + bv.x;
            o.y = acc[ft][st][1] + bv.y;
            o.z = acc[ft][st][2] + bv.z;
            o.w = acc[ft][st][3] + bv.w;
            *(float4*)(out + (size_t)s * 512 + f) = o;
        }
    }
}

// -------------------------------------------------------------- launch ------
extern "C" void kernel_launch(void* const* d_in, const int* in_sizes, int n_in,
                              void* d_out, int out_size, void* d_ws, size_t ws_size,
                              hipStream_t stream)
{
    const float* inQ = (const float*)d_in[0];
    const float* inK = (const float*)d_in[1];
    const float* inV = (const float*)d_in[2];
    const int*   rpm = (const int*)d_in[3];
    const int*   cpm = (const int*)d_in[4];
    const float* WQ  = (const float*)d_in[5];
    const float* bQ  = (const float*)d_in[6];
    const float* WK  = (const float*)d_in[7];
    const float* bK  = (const float*)d_in[8];
    const float* WV  = (const float*)d_in[9];
    const float* bV  = (const float*)d_in[10];
    const float* WO  = (const float*)d_in[11];
    const float* bO  = (const float*)d_in[12];
    float* out = (float*)d_out;

    char* ws = (char*)d_ws;
    unsigned short* Wbf = (unsigned short*)(ws + 12582912);      //  2 MB
    unsigned short* Qg  = (unsigned short*)(ws + 14680064);      //  4 MB
    unsigned short* Kg  = (unsigned short*)(ws + 18874368);      //  4 MB
    unsigned short* VTg = (unsigned short*)(ws + 23068672);      //  4 MB
    unsigned short* AO  = (unsigned short*)(ws + 27262976);      //  4 MB
    int* lens           = (int*)(ws + 31457280);

    cvtlens_kernel<<<dim3(512), dim3(256), 0, stream>>>(
        WQ, WK, WV, WO, rpm, cpm, Wbf, lens);
    proj_gemm<<<dim3(768), dim3(256), 0, stream>>>(
        inQ, inK, inV, Wbf, bQ, bK, bV, lens, Qg, Kg, VTg);
    attn_kernel<<<dim3(1024), dim3(256), 0, stream>>>(Qg, Kg, VTg, lens, AO);
    out_gemm<<<dim3(256), dim3(256), 0, stream>>>(AO, Wbf, bO, lens, out);
}